// Round 1
// 223.249 us; speedup vs baseline: 1.0041x; 1.0041x over previous
//
#include <hip/hip_runtime.h>
#include <math.h>

#define T_STEPS 20

typedef _Float16 half8 __attribute__((ext_vector_type(8)));
typedef _Float16 half4v __attribute__((ext_vector_type(4)));
typedef float f32x4 __attribute__((ext_vector_type(4)));

// fast transcendentals: v_exp + v_rcp (~1e-7 abs err; threshold is 9.7e-3)
__device__ __forceinline__ float sigm(float v) {
  return __builtin_amdgcn_rcpf(1.0f + __expf(-v));
}
__device__ __forceinline__ float tanh_f(float v) {
  return 1.0f - 2.0f * __builtin_amdgcn_rcpf(1.0f + __expf(2.0f * v));
}

// lgkm-only workgroup barrier. __syncthreads() drains vmcnt(0) before
// s_barrier, which synchronously waits the 16 prefetch loads issued just
// before B2 every step (~500-900 cy exposed per step). Cross-wave
// visibility here only ever flows through LDS -> lgkmcnt(0) suffices;
// global loads land in private registers and may stay in flight across
// the barrier (consumed at t+1 under the compiler's own scoreboard wait).
__device__ __forceinline__ void barrier_lgkm() {
  asm volatile("s_waitcnt lgkmcnt(0)" ::: "memory");
  __builtin_amdgcn_s_barrier();
  asm volatile("" ::: "memory");  // keep LDS reads from hoisting above
}

// One block per batch (grid=128; R5: cross-block per-step sync ~60 µs/step —
// unaffordable). 1024 threads = 16 waves. R7 was phase/barrier-latency-bound
// (all pipes <30% on active CUs). This version:
//  - carries Z as the recurrent state: h_carry = Z@a2e^T+b only feeds the
//    next gates, so gates = Z@(Whh@a2eW)^T + folded-bias (exact algebra);
//    op5 and one barrier are gone. 4 barriers/step.
//  - op2-P accumulators stay in REGISTERS across B3 into op3 (same-wave tile
//    assignment) — no P LDS round-trip.
//  - x/edge HBM loads for t+1 issue in step t's tail; with lgkm-only
//    barriers they now genuinely ride ~a full step of latency cover.
//    ZERO per-thread arrays (R1/R2: arrays = scratch = HBM).
// MFMA layouts (verified m89 + R7): A[m=lane&15][k=quad*8+j] from row-major
// [m][k]; B[k][n=lane&15] from row-major [n][k]; D row=4*quad+reg, col=lane&15.
__global__ __launch_bounds__(1024)
void traj_disc(const float* __restrict__ x, const float* __restrict__ dmat,
               const float* __restrict__ bmat, const float* __restrict__ hmat,
               const float* __restrict__ maskp,
               const float* __restrict__ embW, const float* __restrict__ embb,
               const float* __restrict__ Wih, const float* __restrict__ Whh,
               const float* __restrict__ bih, const float* __restrict__ bhh,
               const float* __restrict__ dom,
               const float* __restrict__ e2aW, const float* __restrict__ e2ab,
               const float* __restrict__ spaW, const float* __restrict__ spab,
               const float* __restrict__ a2eW, const float* __restrict__ a2eb,
               const float* __restrict__ clsW, const float* __restrict__ clsb,
               const float* __restrict__ h0p, const float* __restrict__ c0p,
               float* __restrict__ out)
{
  // f16 pitches 40/72 halves (80/144 B: 16B-aligned, <=2-way banks).
  __shared__ __align__(16) _Float16 sgw[128*40];   // Whh[g][h]        (t=0 path)
  __shared__ __align__(16) _Float16 sgwc[128*40];  // (Whh@a2eW)[g][k] (t>0 path)
  __shared__ __align__(16) float4   sgmb[128];     // (M0, M1, b_t0, b_tn)
  __shared__ __align__(16) _Float16 sESaT[32*40];  // (e2aW^T@spaW_a)^T[zk][h]
  __shared__ __align__(16) _Float16 sEStT[32*40];  // (e2aW^T@spaW_t)^T[zk][h]
  __shared__ float bz[32];                          // folded z bias
  __shared__ float sdom[144];
  __shared__ float sm[1280];                        // mask[b] as [n][t]
  __shared__ float sclsc[32];                       // clsW@a2eW fold
  __shared__ float sclsb2[1];
  __shared__ __align__(16) _Float16 sH[64*40];     // h_lstm rows f16 (+h0 at t=0)
  __shared__ __align__(16) _Float16 sw[64*72];     // normalized w[i][j] f16
  __shared__ __align__(16) _Float16 sz_[64*40];    // Z rows f16 (recurrent state)
  __shared__ __align__(16) _Float16 sQT[32*72];    // Q^T[zk][node] f16
  __shared__ __align__(16) float sgates[128*68];   // gates[gate][node] f32

  const int tid = threadIdx.x;
  const int b = blockIdx.x;
  const int i = tid >> 4;     // node 0..63 (nonlin/3a decomposition)
  const int s = tid & 15;     // sub-lane 0..15
  const int w = tid >> 6;     // wave 0..15 (MFMA decomposition)
  const int l = tid & 63;
  const int quad = l >> 4;
  const int n16 = l & 15;

  // ---- one-time staging ----
  for (int idx = tid; idx < 4096; idx += 1024) sgw[(idx >> 5)*40 + (idx & 31)] = (_Float16)Whh[idx];
  {  // Wcomb[g][k] = sum_h Whh[g][h] * a2eW[h][k]; 8 threads per g, 4 k each
    const int g = tid >> 3, kb = (tid & 7) << 2;
    float a0 = 0.f, a1 = 0.f, a2 = 0.f, a3 = 0.f;
    #pragma unroll
    for (int h = 0; h < 32; ++h) {
      const float wv = Whh[g*32 + h];
      a0 = fmaf(wv, a2eW[h*32 + kb + 0], a0);
      a1 = fmaf(wv, a2eW[h*32 + kb + 1], a1);
      a2 = fmaf(wv, a2eW[h*32 + kb + 2], a2);
      a3 = fmaf(wv, a2eW[h*32 + kb + 3], a3);
    }
    sgwc[g*40 + kb + 0] = (_Float16)a0; sgwc[g*40 + kb + 1] = (_Float16)a1;
    sgwc[g*40 + kb + 2] = (_Float16)a2; sgwc[g*40 + kb + 3] = (_Float16)a3;
  }
  if (tid < 128) {  // x-projection fold + both bias variants
    float m0 = 0.f, m1 = 0.f, b0 = bih[tid] + bhh[tid];
    #pragma unroll
    for (int e = 0; e < 16; ++e) {
      float wv_ = Wih[tid*16 + e];
      m0 = fmaf(wv_, embW[2*e],   m0);
      m1 = fmaf(wv_, embW[2*e+1], m1);
      b0 = fmaf(wv_, embb[e],     b0);
    }
    float bn = b0;
    #pragma unroll
    for (int h = 0; h < 32; ++h) bn = fmaf(Whh[tid*32 + h], a2eb[h], bn);
    sgmb[tid] = make_float4(m0, m1, b0, bn);
  }
  {  // ESa^T / ESt^T: entry (zk = tid>>5, h = tid&31)
    const int zk = tid >> 5, hc = tid & 31;
    float sa_ = 0.f, st_ = 0.f;
    #pragma unroll
    for (int a = 0; a < 32; ++a) {
      const float ev = e2aW[a*32 + hc];
      sa_ = fmaf(spaW[zk*64 + a],      ev, sa_);
      st_ = fmaf(spaW[zk*64 + 32 + a], ev, st_);
    }
    sESaT[zk*40 + hc] = (_Float16)sa_;
    sEStT[zk*40 + hc] = (_Float16)st_;
  }
  if (tid < 32) {  // bz fold + classifier fold
    float acc = spab[tid];
    #pragma unroll
    for (int a = 0; a < 32; ++a)
      acc = fmaf(e2ab[a], spaW[tid*64 + a] + spaW[tid*64 + 32 + a], acc);
    bz[tid] = acc;
    float cc = 0.f;
    #pragma unroll
    for (int h = 0; h < 32; ++h) cc = fmaf(clsW[h], a2eW[h*32 + tid], cc);
    sclsc[tid] = cc;
  }
  if (tid == 0) {
    float cb = clsb[0];
    #pragma unroll
    for (int h = 0; h < 32; ++h) cb = fmaf(clsW[h], a2eb[h], cb);
    sclsb2[0] = cb;
  }
  if (tid < 144) sdom[tid] = dom[tid];
  for (int idx = tid; idx < 1280; idx += 1024) sm[idx] = maskp[(size_t)b*1280 + idx];
  for (int idx = tid; idx < 2048; idx += 1024) sH[(idx >> 5)*40 + (idx & 31)] = (_Float16)h0p[(size_t)b*2048 + idx];
  float c0r = c0p[(size_t)b*2048 + i*32 + s];       // cell f32, hh = s
  float c1r = c0p[(size_t)b*2048 + i*32 + s + 16];  // cell f32, hh = s+16
  __syncthreads();

  const size_t nb = (size_t)b*64 + i;

  // ---- prefetched step inputs (NAMED scalars, refreshed in step tail) ----
  const float* xpre = x + (size_t)(b*64 + ((w >> 2) << 4) + (quad << 2)) * 40;
  float2 xA = *(const float2*)(xpre +   0);
  float2 xB = *(const float2*)(xpre +  40);
  float2 xC = *(const float2*)(xpre +  80);
  float2 xD = *(const float2*)(xpre + 120);
  size_t eb_ = nb*1280;   // (nb*20 + 0)*64
  float dm0 = dmat[eb_ + s],      bm0 = bmat[eb_ + s],      hm0 = hmat[eb_ + s];
  float dm1 = dmat[eb_ + s + 16], bm1 = bmat[eb_ + s + 16], hm1 = hmat[eb_ + s + 16];
  float dm2 = dmat[eb_ + s + 32], bm2 = bmat[eb_ + s + 32], hm2 = hmat[eb_ + s + 32];
  float dm3 = dmat[eb_ + s + 48], bm3 = bmat[eb_ + s + 48], hm3 = hmat[eb_ + s + 48];

  #pragma unroll 1
  for (int t = 0; t < T_STEPS; ++t) {
    // ---- op1: Gates[node][g] = State @ W^T + x-part. 32 tiles, 2/wave.
    // t=0: State=h0 (sH), W=Whh; t>0: State=Z (sz_), W=Wcomb. Wave-uniform. ----
    {
      const int r1 = w >> 2, cp = (w & 3) << 1;
      const _Float16* Abase = (t == 0) ? sH : sz_;
      const _Float16* Bbase = (t == 0) ? sgw : sgwc;
      const half8 Af = *(const half8*)(Abase + (16*r1 + n16)*40 + quad*8);
#define OP1C(c) { \
      const half8 Bf = *(const half8*)(Bbase + (16*(c) + n16)*40 + quad*8); \
      const float4 mb = sgmb[16*(c) + n16]; \
      const float bb = (t == 0) ? mb.z : mb.w; \
      f32x4 Cv; \
      Cv[0] = fmaf(xA.x, mb.x, fmaf(xA.y, mb.y, bb)); \
      Cv[1] = fmaf(xB.x, mb.x, fmaf(xB.y, mb.y, bb)); \
      Cv[2] = fmaf(xC.x, mb.x, fmaf(xC.y, mb.y, bb)); \
      Cv[3] = fmaf(xD.x, mb.x, fmaf(xD.y, mb.y, bb)); \
      Cv = __builtin_amdgcn_mfma_f32_16x16x32_f16(Af, Bf, Cv, 0, 0, 0); \
      *(f32x4*)(sgates + (16*(c) + n16)*68 + 16*r1 + 4*quad) = Cv; }
      OP1C(cp) OP1C(cp + 1)
#undef OP1C
    }
    barrier_lgkm();  // B1: gates visible

    // ---- nonlin: LSTM cell per (i, hh = s + 16u); c stays in this lane ----
    {
#define GR(q, u) sgates[((q)*32 + s + 16*(u))*68 + i]
      const float ai0 = GR(0,0), af0 = GR(1,0), ag0 = GR(2,0), ao0 = GR(3,0);
      const float ai1 = GR(0,1), af1 = GR(1,1), ag1 = GR(2,1), ao1 = GR(3,1);
#undef GR
      c0r = fmaf(sigm(af0), c0r, sigm(ai0)*tanh_f(ag0));
      sH[i*40 + s]      = (_Float16)(sigm(ao0)*tanh_f(c0r));
      c1r = fmaf(sigm(af1), c1r, sigm(ai1)*tanh_f(ag1));
      sH[i*40 + s + 16] = (_Float16)(sigm(ao1)*tanh_f(c1r));
    }
    // ---- 3a: normalized edge weights -> sw[i][j] f16 (row-local) ----
    {
      const float mi_ = sm[i*20 + t];
      float rs = 0.0f;
#define WCOMP(jj) float wn##jj; { \
      int ib_ = (int)floorf(bm##jj * (1.0f/30.0f)); ib_ = ib_ < 0 ? 0 : (ib_ > 11 ? 11 : ib_); \
      int ih_ = (int)floorf(hm##jj * (1.0f/30.0f)); ih_ = ih_ < 0 ? 0 : (ih_ > 11 ? 11 : ih_); \
      float w_ = fmaxf(sdom[ib_*12 + ih_] - dm##jj, 0.0f) * (mi_ * sm[(s + 16*(jj))*20 + t]); \
      wn##jj = (s + 16*(jj) == i) ? 0.0f : w_; rs += wn##jj; }
      WCOMP(0) WCOMP(1) WCOMP(2) WCOMP(3)
#undef WCOMP
      rs += __shfl_xor(rs, 1); rs += __shfl_xor(rs, 2);
      rs += __shfl_xor(rs, 4); rs += __shfl_xor(rs, 8);
      const float inv_ = __builtin_amdgcn_rcpf(rs + 1e-12f);
      sw[i*72 + s +  0] = (_Float16)(wn0 * inv_);
      sw[i*72 + s + 16] = (_Float16)(wn1 * inv_);
      sw[i*72 + s + 32] = (_Float16)(wn2 * inv_);
      sw[i*72 + s + 48] = (_Float16)(wn3 * inv_);
    }
    // ---- prefetch t+1 inputs (edges + x): rides across the lgkm-only
    //      barriers for ~a full step of latency cover ----
    {
      const int tn = (t < T_STEPS - 1) ? t + 1 : t;
      const size_t ebn = (nb*20 + tn)*64;
      dm0 = dmat[ebn + s];      bm0 = bmat[ebn + s];      hm0 = hmat[ebn + s];
      dm1 = dmat[ebn + s + 16]; bm1 = bmat[ebn + s + 16]; hm1 = hmat[ebn + s + 16];
      dm2 = dmat[ebn + s + 32]; bm2 = bmat[ebn + s + 32]; hm2 = hmat[ebn + s + 32];
      dm3 = dmat[ebn + s + 48]; bm3 = bmat[ebn + s + 48]; hm3 = hmat[ebn + s + 48];
      const int tn2 = tn << 1;
      xA = *(const float2*)(xpre + tn2);
      xB = *(const float2*)(xpre + tn2 +  40);
      xC = *(const float2*)(xpre + tn2 +  80);
      xD = *(const float2*)(xpre + tn2 + 120);
    }
    barrier_lgkm();  // B2: h_lstm + w visible (prefetch stays in flight)

    // ---- op2: waves 0-7 P = H@ESa + bz (REGISTERS); waves 8-15 Q -> sQT ----
    f32x4 Pv = {0.f, 0.f, 0.f, 0.f};
    if (w < 8) {
      const int r = w >> 1, c = w & 1;
      const half8 Af = *(const half8*)(sH    + (16*r + n16)*40 + quad*8);
      const half8 Bf = *(const half8*)(sESaT + (16*c + n16)*40 + quad*8);
      const float bzv = bz[16*c + n16];
      Pv[0] = bzv; Pv[1] = bzv; Pv[2] = bzv; Pv[3] = bzv;
      Pv = __builtin_amdgcn_mfma_f32_16x16x32_f16(Af, Bf, Pv, 0, 0, 0);
    } else {
      const int w8 = w - 8, r = w8 >> 1, c = w8 & 1;
      const half8 Af = *(const half8*)(sH    + (16*r + n16)*40 + quad*8);
      const half8 Bf = *(const half8*)(sEStT + (16*c + n16)*40 + quad*8);
      f32x4 Cv = {0.f, 0.f, 0.f, 0.f};
      Cv = __builtin_amdgcn_mfma_f32_16x16x32_f16(Af, Bf, Cv, 0, 0, 0);
      half4v hq;
      hq[0] = (_Float16)Cv[0]; hq[1] = (_Float16)Cv[1];
      hq[2] = (_Float16)Cv[2]; hq[3] = (_Float16)Cv[3];
      *(half4v*)(sQT + (16*c + n16)*72 + 16*r + 4*quad) = hq;
    }
    barrier_lgkm();  // B3: Q^T visible (P rides in registers)

    // ---- op3: Z = tanh(Pv + Wn@Q) (waves 0-7, same tile as their P) ----
    if (w < 8) {
      const int r = w >> 1, c = w & 1;
      const half8 A0 = *(const half8*)(sw  + (16*r + n16)*72 + quad*8);
      const half8 A1 = *(const half8*)(sw  + (16*r + n16)*72 + 32 + quad*8);
      const half8 B0 = *(const half8*)(sQT + (16*c + n16)*72 + quad*8);
      const half8 B1 = *(const half8*)(sQT + (16*c + n16)*72 + 32 + quad*8);
      Pv = __builtin_amdgcn_mfma_f32_16x16x32_f16(A0, B0, Pv, 0, 0, 0);
      Pv = __builtin_amdgcn_mfma_f32_16x16x32_f16(A1, B1, Pv, 0, 0, 0);
      const int nd = 16*r + 4*quad;
      sz_[(nd+0)*40 + 16*c + n16] = (_Float16)tanh_f(Pv[0]);
      sz_[(nd+1)*40 + 16*c + n16] = (_Float16)tanh_f(Pv[1]);
      sz_[(nd+2)*40 + 16*c + n16] = (_Float16)tanh_f(Pv[2]);
      sz_[(nd+3)*40 + 16*c + n16] = (_Float16)tanh_f(Pv[3]);
    }
    barrier_lgkm();  // Bend: Z final for this step (op1(t+1) reads it)
  }

  // ---- classifier head (folded through a2e): out = sigm(tanh(z.clsc + b)) ----
  if (tid < 64) {
    float acc = sclsb2[0];
    #pragma unroll
    for (int k = 0; k < 32; ++k) acc = fmaf((float)sz_[tid*40 + k], sclsc[k], acc);
    out[(size_t)b*64 + tid] = sigm(tanh_f(acc));
  }
}

extern "C" void kernel_launch(void* const* d_in, const int* in_sizes, int n_in,
                              void* d_out, int out_size, void* d_ws, size_t ws_size,
                              hipStream_t stream) {
  (void)in_sizes; (void)n_in; (void)d_ws; (void)ws_size; (void)out_size;
  const float* x    = (const float*)d_in[0];
  const float* dmat = (const float*)d_in[1];
  const float* bmat = (const float*)d_in[2];
  const float* hmat = (const float*)d_in[3];
  const float* mask = (const float*)d_in[4];
  const float* embW = (const float*)d_in[5];
  const float* embb = (const float*)d_in[6];
  const float* Wih  = (const float*)d_in[7];
  const float* Whh  = (const float*)d_in[8];
  const float* bih  = (const float*)d_in[9];
  const float* bhh  = (const float*)d_in[10];
  const float* dom  = (const float*)d_in[11];
  const float* e2aW = (const float*)d_in[12];
  const float* e2ab = (const float*)d_in[13];
  const float* spaW = (const float*)d_in[14];
  const float* spab = (const float*)d_in[15];
  const float* a2eW = (const float*)d_in[16];
  const float* a2eb = (const float*)d_in[17];
  const float* clsW = (const float*)d_in[18];
  const float* clsb = (const float*)d_in[19];
  const float* h0   = (const float*)d_in[20];
  const float* c0   = (const float*)d_in[21];
  float* out = (float*)d_out;

  traj_disc<<<dim3(128), dim3(1024), 0, stream>>>(
      x, dmat, bmat, hmat, mask, embW, embb, Wih, Whh, bih, bhh, dom,
      e2aW, e2ab, spaW, spab, a2eW, a2eb, clsW, clsb, h0, c0, out);
}

// Round 2
// 206.380 us; speedup vs baseline: 1.0861x; 1.0817x over previous
//
#include <hip/hip_runtime.h>
#include <math.h>

#define T_STEPS 20

typedef _Float16 half8 __attribute__((ext_vector_type(8)));
typedef _Float16 half4v __attribute__((ext_vector_type(4)));
typedef float f32x4 __attribute__((ext_vector_type(4)));

// fast transcendentals: v_exp + v_rcp (~1e-7 abs err; threshold is 9.7e-3)
__device__ __forceinline__ float sigm(float v) {
  return __builtin_amdgcn_rcpf(1.0f + __expf(-v));
}
__device__ __forceinline__ float tanh_f(float v) {
  return 1.0f - 2.0f * __builtin_amdgcn_rcpf(1.0f + __expf(2.0f * v));
}

// lgkm-only workgroup barrier: cross-wave visibility only flows through LDS;
// global prefetch loads stay in flight across it (R1: neutral vs syncthreads,
// kept because it is never worse and lets edge/x prefetch ride 2+ phases).
__device__ __forceinline__ void barrier_lgkm() {
  asm volatile("s_waitcnt lgkmcnt(0)" ::: "memory");
  __builtin_amdgcn_s_barrier();
  asm volatile("" ::: "memory");
}

// One block per batch (grid=128; R5: cross-block per-step sync unaffordable).
// 1024 threads = 16 waves. R8 (this version): op1+LSTM nonlin FUSED in
// registers. A wave (r = w>>1, u = w&1) computes all 4 gate-column tiles
// c = 2q+u for its (node-tile r, hh-tile u): after 4 MFMAs, lane (quad,n16)
// holds gate pre-acts i,f,g,o for nodes 16r+4quad+{0..3}, hh = 16u+n16 —
// the LSTM cell runs in-lane (cell state ccell[4] lives in the same layout).
// sgates (34.8 KB, 8-way-conflict b128 writes) and barrier B1 are GONE:
// 3 barriers/step. Waves 8-15 concurrently compute 3a edge weights
// (8 threads/node, 8 contiguous j each, vectorized f32x4 edge loads, half8
// row-chunk store). h0 staged into sz_ so t=0's op1 A-read never races the
// fused sH writes. ZERO runtime-indexed per-thread arrays (R1/R2).
// MFMA layouts (verified m89 + R7): A[m=lane&15][k=quad*8+j] from row-major
// [m][k]; B[k][n=lane&15] from row-major [n][k]; D row=4*quad+reg, col=lane&15.
__global__ __launch_bounds__(1024)
void traj_disc(const float* __restrict__ x, const float* __restrict__ dmat,
               const float* __restrict__ bmat, const float* __restrict__ hmat,
               const float* __restrict__ maskp,
               const float* __restrict__ embW, const float* __restrict__ embb,
               const float* __restrict__ Wih, const float* __restrict__ Whh,
               const float* __restrict__ bih, const float* __restrict__ bhh,
               const float* __restrict__ dom,
               const float* __restrict__ e2aW, const float* __restrict__ e2ab,
               const float* __restrict__ spaW, const float* __restrict__ spab,
               const float* __restrict__ a2eW, const float* __restrict__ a2eb,
               const float* __restrict__ clsW, const float* __restrict__ clsb,
               const float* __restrict__ h0p, const float* __restrict__ c0p,
               float* __restrict__ out)
{
  // f16 pitches 40/72 halves (80/144 B: 16B-aligned, <=2-way banks).
  __shared__ __align__(16) _Float16 sgw[128*40];   // Whh[g][h]        (t=0 path)
  __shared__ __align__(16) _Float16 sgwc[128*40];  // (Whh@a2eW)[g][k] (t>0 path)
  __shared__ __align__(16) float4   sgmb[128];     // (M0, M1, b_t0, b_tn)
  __shared__ __align__(16) _Float16 sESaT[32*40];  // (e2aW^T@spaW_a)^T[zk][h]
  __shared__ __align__(16) _Float16 sEStT[32*40];  // (e2aW^T@spaW_t)^T[zk][h]
  __shared__ float bz[32];                          // folded z bias
  __shared__ float sdom[144];
  __shared__ float sm[1280];                        // mask[b] as [n][t]
  __shared__ float sclsc[32];                       // clsW@a2eW fold
  __shared__ float sclsb2[1];
  __shared__ __align__(16) _Float16 sH[64*40];     // h_lstm rows f16
  __shared__ __align__(16) _Float16 sw[64*72];     // normalized w[i][j] f16
  __shared__ __align__(16) _Float16 sz_[64*40];    // Z rows f16 (recurrent state; h0 at t=0)
  __shared__ __align__(16) _Float16 sQT[32*72];    // Q^T[zk][node] f16

  const int tid = threadIdx.x;
  const int b = blockIdx.x;
  const int w = tid >> 6;     // wave 0..15
  const int l = tid & 63;
  const int quad = l >> 4;
  const int n16 = l & 15;

  // ---- one-time staging ----
  for (int idx = tid; idx < 4096; idx += 1024) sgw[(idx >> 5)*40 + (idx & 31)] = (_Float16)Whh[idx];
  {  // Wcomb[g][k] = sum_h Whh[g][h] * a2eW[h][k]; 8 threads per g, 4 k each
    const int g = tid >> 3, kb = (tid & 7) << 2;
    float a0 = 0.f, a1 = 0.f, a2 = 0.f, a3 = 0.f;
    #pragma unroll
    for (int h = 0; h < 32; ++h) {
      const float wv = Whh[g*32 + h];
      a0 = fmaf(wv, a2eW[h*32 + kb + 0], a0);
      a1 = fmaf(wv, a2eW[h*32 + kb + 1], a1);
      a2 = fmaf(wv, a2eW[h*32 + kb + 2], a2);
      a3 = fmaf(wv, a2eW[h*32 + kb + 3], a3);
    }
    sgwc[g*40 + kb + 0] = (_Float16)a0; sgwc[g*40 + kb + 1] = (_Float16)a1;
    sgwc[g*40 + kb + 2] = (_Float16)a2; sgwc[g*40 + kb + 3] = (_Float16)a3;
  }
  if (tid < 128) {  // x-projection fold + both bias variants
    float m0 = 0.f, m1 = 0.f, b0 = bih[tid] + bhh[tid];
    #pragma unroll
    for (int e = 0; e < 16; ++e) {
      float wv_ = Wih[tid*16 + e];
      m0 = fmaf(wv_, embW[2*e],   m0);
      m1 = fmaf(wv_, embW[2*e+1], m1);
      b0 = fmaf(wv_, embb[e],     b0);
    }
    float bn = b0;
    #pragma unroll
    for (int h = 0; h < 32; ++h) bn = fmaf(Whh[tid*32 + h], a2eb[h], bn);
    sgmb[tid] = make_float4(m0, m1, b0, bn);
  }
  {  // ESa^T / ESt^T: entry (zk = tid>>5, h = tid&31)
    const int zk = tid >> 5, hc = tid & 31;
    float sa_ = 0.f, st_ = 0.f;
    #pragma unroll
    for (int a = 0; a < 32; ++a) {
      const float ev = e2aW[a*32 + hc];
      sa_ = fmaf(spaW[zk*64 + a],      ev, sa_);
      st_ = fmaf(spaW[zk*64 + 32 + a], ev, st_);
    }
    sESaT[zk*40 + hc] = (_Float16)sa_;
    sEStT[zk*40 + hc] = (_Float16)st_;
  }
  if (tid < 32) {  // bz fold + classifier fold
    float acc = spab[tid];
    #pragma unroll
    for (int a = 0; a < 32; ++a)
      acc = fmaf(e2ab[a], spaW[tid*64 + a] + spaW[tid*64 + 32 + a], acc);
    bz[tid] = acc;
    float cc = 0.f;
    #pragma unroll
    for (int h = 0; h < 32; ++h) cc = fmaf(clsW[h], a2eW[h*32 + tid], cc);
    sclsc[tid] = cc;
  }
  if (tid == 0) {
    float cb = clsb[0];
    #pragma unroll
    for (int h = 0; h < 32; ++h) cb = fmaf(clsW[h], a2eb[h], cb);
    sclsb2[0] = cb;
  }
  if (tid < 144) sdom[tid] = dom[tid];
  for (int idx = tid; idx < 1280; idx += 1024) sm[idx] = maskp[(size_t)b*1280 + idx];
  // h0 -> sz_ (t=0 op1 reads sz_; sH is written fresh every step pre-B2)
  for (int idx = tid; idx < 2048; idx += 1024) sz_[(idx >> 5)*40 + (idx & 31)] = (_Float16)h0p[(size_t)b*2048 + idx];

  // cell state in the fused-gate layout: waves 0-7, lane (quad,n16) of wave
  // (r=w>>1, u=w&1) owns nodes 16r+4quad+{0..3}, hh = 16u+n16.
  f32x4 ccell;
  float2 xA, xB, xC, xD;
  f32x4 dmv0, dmv1, bmv0, bmv1, hmv0, hmv1;
  const float* xpre = nullptr;
  size_t ebp = 0;
  if (w < 8) {
    const int rr = w >> 1, uu = w & 1;
    const int hh = 16*uu + n16;
    #pragma unroll
    for (int reg = 0; reg < 4; ++reg)
      ccell[reg] = c0p[(size_t)b*2048 + (size_t)(16*rr + 4*quad + reg)*32 + hh];
    xpre = x + (size_t)(b*64 + 16*rr + 4*quad) * 40;
    xA = *(const float2*)(xpre +   0);
    xB = *(const float2*)(xpre +  40);
    xC = *(const float2*)(xpre +  80);
    xD = *(const float2*)(xpre + 120);
  } else {
    const int i8 = (tid - 512) >> 3, s8 = tid & 7;
    ebp = ((size_t)(b*64 + i8)*20)*64 + (size_t)(s8*8);
    dmv0 = *(const f32x4*)(dmat + ebp); dmv1 = *(const f32x4*)(dmat + ebp + 4);
    bmv0 = *(const f32x4*)(bmat + ebp); bmv1 = *(const f32x4*)(bmat + ebp + 4);
    hmv0 = *(const f32x4*)(hmat + ebp); hmv1 = *(const f32x4*)(hmat + ebp + 4);
  }
  __syncthreads();

  #pragma unroll 1
  for (int t = 0; t < T_STEPS; ++t) {
    // ---- phase A: waves 0-7 fused op1+nonlin; waves 8-15 edge weights ----
    if (w < 8) {
      const int rr = w >> 1, uu = w & 1;
      const _Float16* Bbase = (t == 0) ? sgw : sgwc;
      const half8 Af = *(const half8*)(sz_ + (16*rr + n16)*40 + quad*8);
      f32x4 G0, G1, G2, G3;
#define OP1Q(Gq, q) { \
      const int c_ = 2*(q) + uu; \
      const half8 Bf = *(const half8*)(Bbase + (16*c_ + n16)*40 + quad*8); \
      const float4 mb = sgmb[16*c_ + n16]; \
      const float bb = (t == 0) ? mb.z : mb.w; \
      f32x4 Cv; \
      Cv[0] = fmaf(xA.x, mb.x, fmaf(xA.y, mb.y, bb)); \
      Cv[1] = fmaf(xB.x, mb.x, fmaf(xB.y, mb.y, bb)); \
      Cv[2] = fmaf(xC.x, mb.x, fmaf(xC.y, mb.y, bb)); \
      Cv[3] = fmaf(xD.x, mb.x, fmaf(xD.y, mb.y, bb)); \
      Gq = __builtin_amdgcn_mfma_f32_16x16x32_f16(Af, Bf, Cv, 0, 0, 0); }
      OP1Q(G0, 0) OP1Q(G1, 1) OP1Q(G2, 2) OP1Q(G3, 3)
#undef OP1Q
      // LSTM nonlin, fully in-register (gate order i,f,g,o = q 0..3)
      const int hh = 16*uu + n16;
      #pragma unroll
      for (int reg = 0; reg < 4; ++reg) {
        const float cc = fmaf(sigm(G1[reg]), ccell[reg], sigm(G0[reg]) * tanh_f(G2[reg]));
        ccell[reg] = cc;
        sH[(16*rr + 4*quad + reg)*40 + hh] = (_Float16)(sigm(G3[reg]) * tanh_f(cc));
      }
      // x prefetch t+1 (rides across lgkm-only barriers)
      const int tn2 = ((t < T_STEPS - 1) ? t + 1 : t) << 1;
      xA = *(const float2*)(xpre + tn2);
      xB = *(const float2*)(xpre + tn2 +  40);
      xC = *(const float2*)(xpre + tn2 +  80);
      xD = *(const float2*)(xpre + tn2 + 120);
    } else {
      const int i8 = (tid - 512) >> 3, s8 = tid & 7;
      const float mi_ = sm[i8*20 + t];
      f32x4 wnA, wnB;
      float rs = 0.0f;
#define WC(dst, k, dmv, bmv, hmv, jof) { \
      int ib_ = (int)floorf(bmv[k] * (1.0f/30.0f)); ib_ = ib_ < 0 ? 0 : (ib_ > 11 ? 11 : ib_); \
      int ih_ = (int)floorf(hmv[k] * (1.0f/30.0f)); ih_ = ih_ < 0 ? 0 : (ih_ > 11 ? 11 : ih_); \
      float w_ = fmaxf(sdom[ib_*12 + ih_] - dmv[k], 0.0f) * (mi_ * sm[(8*s8 + (jof))*20 + t]); \
      w_ = (8*s8 + (jof) == i8) ? 0.0f : w_; dst[k] = w_; rs += w_; }
      WC(wnA,0,dmv0,bmv0,hmv0,0) WC(wnA,1,dmv0,bmv0,hmv0,1)
      WC(wnA,2,dmv0,bmv0,hmv0,2) WC(wnA,3,dmv0,bmv0,hmv0,3)
      WC(wnB,0,dmv1,bmv1,hmv1,4) WC(wnB,1,dmv1,bmv1,hmv1,5)
      WC(wnB,2,dmv1,bmv1,hmv1,6) WC(wnB,3,dmv1,bmv1,hmv1,7)
#undef WC
      rs += __shfl_xor(rs, 1); rs += __shfl_xor(rs, 2); rs += __shfl_xor(rs, 4);
      const float inv_ = __builtin_amdgcn_rcpf(rs + 1e-12f);
      half8 hw;
      hw[0] = (_Float16)(wnA[0]*inv_); hw[1] = (_Float16)(wnA[1]*inv_);
      hw[2] = (_Float16)(wnA[2]*inv_); hw[3] = (_Float16)(wnA[3]*inv_);
      hw[4] = (_Float16)(wnB[0]*inv_); hw[5] = (_Float16)(wnB[1]*inv_);
      hw[6] = (_Float16)(wnB[2]*inv_); hw[7] = (_Float16)(wnB[3]*inv_);
      *(half8*)(sw + i8*72 + s8*8) = hw;
      // edge prefetch t+1
      const int tn = (t < T_STEPS - 1) ? t + 1 : t;
      const size_t eb2 = ebp + (size_t)tn*64;
      dmv0 = *(const f32x4*)(dmat + eb2); dmv1 = *(const f32x4*)(dmat + eb2 + 4);
      bmv0 = *(const f32x4*)(bmat + eb2); bmv1 = *(const f32x4*)(bmat + eb2 + 4);
      hmv0 = *(const f32x4*)(hmat + eb2); hmv1 = *(const f32x4*)(hmat + eb2 + 4);
    }
    barrier_lgkm();  // B2: h_lstm + w visible

    // ---- op2: waves 0-7 P = H@ESa + bz (REGISTERS); waves 8-15 Q -> sQT ----
    f32x4 Pv = {0.f, 0.f, 0.f, 0.f};
    if (w < 8) {
      const int r = w >> 1, c = w & 1;
      const half8 Af = *(const half8*)(sH    + (16*r + n16)*40 + quad*8);
      const half8 Bf = *(const half8*)(sESaT + (16*c + n16)*40 + quad*8);
      const float bzv = bz[16*c + n16];
      Pv[0] = bzv; Pv[1] = bzv; Pv[2] = bzv; Pv[3] = bzv;
      Pv = __builtin_amdgcn_mfma_f32_16x16x32_f16(Af, Bf, Pv, 0, 0, 0);
    } else {
      const int w8 = w - 8, r = w8 >> 1, c = w8 & 1;
      const half8 Af = *(const half8*)(sH    + (16*r + n16)*40 + quad*8);
      const half8 Bf = *(const half8*)(sEStT + (16*c + n16)*40 + quad*8);
      f32x4 Cv = {0.f, 0.f, 0.f, 0.f};
      Cv = __builtin_amdgcn_mfma_f32_16x16x32_f16(Af, Bf, Cv, 0, 0, 0);
      half4v hq;
      hq[0] = (_Float16)Cv[0]; hq[1] = (_Float16)Cv[1];
      hq[2] = (_Float16)Cv[2]; hq[3] = (_Float16)Cv[3];
      *(half4v*)(sQT + (16*c + n16)*72 + 16*r + 4*quad) = hq;
    }
    barrier_lgkm();  // B3: Q^T visible (P rides in registers)

    // ---- op3: Z = tanh(Pv + Wn@Q) (waves 0-7, same tile as their P) ----
    if (w < 8) {
      const int r = w >> 1, c = w & 1;
      const half8 A0 = *(const half8*)(sw  + (16*r + n16)*72 + quad*8);
      const half8 A1 = *(const half8*)(sw  + (16*r + n16)*72 + 32 + quad*8);
      const half8 B0 = *(const half8*)(sQT + (16*c + n16)*72 + quad*8);
      const half8 B1 = *(const half8*)(sQT + (16*c + n16)*72 + 32 + quad*8);
      Pv = __builtin_amdgcn_mfma_f32_16x16x32_f16(A0, B0, Pv, 0, 0, 0);
      Pv = __builtin_amdgcn_mfma_f32_16x16x32_f16(A1, B1, Pv, 0, 0, 0);
      const int nd = 16*r + 4*quad;
      sz_[(nd+0)*40 + 16*c + n16] = (_Float16)tanh_f(Pv[0]);
      sz_[(nd+1)*40 + 16*c + n16] = (_Float16)tanh_f(Pv[1]);
      sz_[(nd+2)*40 + 16*c + n16] = (_Float16)tanh_f(Pv[2]);
      sz_[(nd+3)*40 + 16*c + n16] = (_Float16)tanh_f(Pv[3]);
    }
    barrier_lgkm();  // Bend: Z final for this step (op1(t+1) reads it)
  }

  // ---- classifier head (folded through a2e): out = sigm(tanh(z.clsc + b)) ----
  if (tid < 64) {
    float acc = sclsb2[0];
    #pragma unroll
    for (int k = 0; k < 32; ++k) acc = fmaf((float)sz_[tid*40 + k], sclsc[k], acc);
    out[(size_t)b*64 + tid] = sigm(tanh_f(acc));
  }
}

extern "C" void kernel_launch(void* const* d_in, const int* in_sizes, int n_in,
                              void* d_out, int out_size, void* d_ws, size_t ws_size,
                              hipStream_t stream) {
  (void)in_sizes; (void)n_in; (void)d_ws; (void)ws_size; (void)out_size;
  const float* x    = (const float*)d_in[0];
  const float* dmat = (const float*)d_in[1];
  const float* bmat = (const float*)d_in[2];
  const float* hmat = (const float*)d_in[3];
  const float* mask = (const float*)d_in[4];
  const float* embW = (const float*)d_in[5];
  const float* embb = (const float*)d_in[6];
  const float* Wih  = (const float*)d_in[7];
  const float* Whh  = (const float*)d_in[8];
  const float* bih  = (const float*)d_in[9];
  const float* bhh  = (const float*)d_in[10];
  const float* dom  = (const float*)d_in[11];
  const float* e2aW = (const float*)d_in[12];
  const float* e2ab = (const float*)d_in[13];
  const float* spaW = (const float*)d_in[14];
  const float* spab = (const float*)d_in[15];
  const float* a2eW = (const float*)d_in[16];
  const float* a2eb = (const float*)d_in[17];
  const float* clsW = (const float*)d_in[18];
  const float* clsb = (const float*)d_in[19];
  const float* h0   = (const float*)d_in[20];
  const float* c0   = (const float*)d_in[21];
  float* out = (float*)d_out;

  traj_disc<<<dim3(128), dim3(1024), 0, stream>>>(
      x, dmat, bmat, hmat, mask, embW, embb, Wih, Whh, bih, bhh, dom,
      e2aW, e2ab, spaW, spab, a2eW, a2eb, clsW, clsb, h0, c0, out);
}